// Round 1
// baseline (1276.414 us; speedup 1.0000x reference)
//
#include <hip/hip_runtime.h>

#define HDIM 64

__device__ __forceinline__ float fast_sigmoid(float v) {
    // 1 / (1 + 2^(-v*log2e))
    return __builtin_amdgcn_rcpf(1.0f + __builtin_amdgcn_exp2f(-1.442695041f * v));
}

__device__ __forceinline__ float fast_tanh(float v) {
    // 1 - 2/(1 + 2^(v*2*log2e))
    return 1.0f - 2.0f * __builtin_amdgcn_rcpf(1.0f + __builtin_amdgcn_exp2f(2.885390082f * v));
}

__global__ __launch_bounds__(64, 1)
void bilstm_kernel(const float* __restrict__ x,
                   const float* __restrict__ w_ih_f,
                   const float* __restrict__ w_hh_f,
                   const float* __restrict__ b_ih_f,
                   const float* __restrict__ b_hh_f,
                   const float* __restrict__ w_ih_b,
                   const float* __restrict__ b_ih_b,
                   const float* __restrict__ b_hh_b,
                   const float* __restrict__ w_fc,
                   const float* __restrict__ b_fc,
                   float* __restrict__ out,
                   int T)
{
    const int b = blockIdx.x;   // batch element
    const int l = threadIdx.x;  // 0..63, owns gates {l, 64+l, 128+l, 192+l} and h[l], c[l]

    __shared__ float hbuf[HDIM];

    // ---- load per-lane weights into registers ----
    // recurrent weights: wh[j][k] = w_hh_f[(j*64 + l)*64 + k]   (j: i,f,g,o)
    float wh[4][HDIM];
    #pragma unroll
    for (int j = 0; j < 4; ++j) {
        const float* row = w_hh_f + (size_t)(j * 64 + l) * HDIM;
        #pragma unroll
        for (int q = 0; q < 16; ++q) {
            float4 r = *(const float4*)(row + 4 * q);
            wh[j][4 * q + 0] = r.x;
            wh[j][4 * q + 1] = r.y;
            wh[j][4 * q + 2] = r.z;
            wh[j][4 * q + 3] = r.w;
        }
    }

    // input weights (IN=4) and fused bias
    float wx[4][4];
    float bz[4];
    #pragma unroll
    for (int j = 0; j < 4; ++j) {
        float4 r = *(const float4*)(w_ih_f + (size_t)(j * 64 + l) * 4);
        wx[j][0] = r.x; wx[j][1] = r.y; wx[j][2] = r.z; wx[j][3] = r.w;
        bz[j] = b_ih_f[j * 64 + l] + b_hh_f[j * 64 + l];
    }

    // ---- forward LSTM over T steps ----
    float c = 0.0f, h = 0.0f;
    hbuf[l] = 0.0f;
    __syncthreads();

    const float* xb = x + (size_t)b * T * 4;

    for (int t = 0; t < T; ++t) {
        // same-address 16B load for all lanes; consumed only after the k-loop
        float4 xt = *(const float4*)(xb + 4 * t);

        float a0 = bz[0], a1 = bz[1], a2 = bz[2], a3 = bz[3];

        #pragma unroll
        for (int q = 0; q < 16; ++q) {
            float4 hq = ((const float4*)hbuf)[q];  // broadcast read
            a0 += wh[0][4 * q + 0] * hq.x; a1 += wh[1][4 * q + 0] * hq.x;
            a2 += wh[2][4 * q + 0] * hq.x; a3 += wh[3][4 * q + 0] * hq.x;
            a0 += wh[0][4 * q + 1] * hq.y; a1 += wh[1][4 * q + 1] * hq.y;
            a2 += wh[2][4 * q + 1] * hq.y; a3 += wh[3][4 * q + 1] * hq.y;
            a0 += wh[0][4 * q + 2] * hq.z; a1 += wh[1][4 * q + 2] * hq.z;
            a2 += wh[2][4 * q + 2] * hq.z; a3 += wh[3][4 * q + 2] * hq.z;
            a0 += wh[0][4 * q + 3] * hq.w; a1 += wh[1][4 * q + 3] * hq.w;
            a2 += wh[2][4 * q + 3] * hq.w; a3 += wh[3][4 * q + 3] * hq.w;
        }

        // input contribution (IN = 4)
        a0 += wx[0][0] * xt.x + wx[0][1] * xt.y + wx[0][2] * xt.z + wx[0][3] * xt.w;
        a1 += wx[1][0] * xt.x + wx[1][1] * xt.y + wx[1][2] * xt.z + wx[1][3] * xt.w;
        a2 += wx[2][0] * xt.x + wx[2][1] * xt.y + wx[2][2] * xt.z + wx[2][3] * xt.w;
        a3 += wx[3][0] * xt.x + wx[3][1] * xt.y + wx[3][2] * xt.z + wx[3][3] * xt.w;

        float gi = fast_sigmoid(a0);
        float gf = fast_sigmoid(a1);
        float gg = fast_tanh(a2);
        float go = fast_sigmoid(a3);
        c = gf * c + gi * gg;
        h = go * fast_tanh(c);

        __syncthreads();            // reads of hbuf above are done (single wave anyway)
        hbuf[l] = h;
        __syncthreads();            // make h visible for next step's reads
    }

    // ---- backward-direction cell: single step from zero state at x[:, T-1] ----
    // h0 = c0 = 0  =>  gates = x_last @ w_ih_b^T + (b_ih_b + b_hh_b); w_hh_b unused.
    float4 xl = *(const float4*)(xb + 4 * (T - 1));
    float gb[4];
    #pragma unroll
    for (int j = 0; j < 4; ++j) {
        float4 r = *(const float4*)(w_ih_b + (size_t)(j * 64 + l) * 4);
        gb[j] = b_ih_b[j * 64 + l] + b_hh_b[j * 64 + l]
              + r.x * xl.x + r.y * xl.y + r.z * xl.z + r.w * xl.w;
    }
    float ib = fast_sigmoid(gb[0]);
    // f gate multiplies c0 = 0 -> irrelevant
    float ggb = fast_tanh(gb[2]);
    float ob = fast_sigmoid(gb[3]);
    float cb = ib * ggb;
    float hb = ob * fast_tanh(cb);

    // ---- fc + sigmoid: logits[b] = sum_l (w_fc[l]*h_l + w_fc[64+l]*hb_l) + b_fc ----
    float p = w_fc[l] * h + w_fc[HDIM + l] * hb;
    #pragma unroll
    for (int off = 32; off; off >>= 1)
        p += __shfl_xor(p, off);

    if (l == 0)
        out[b] = fast_sigmoid(p + b_fc[0]);
}

extern "C" void kernel_launch(void* const* d_in, const int* in_sizes, int n_in,
                              void* d_out, int out_size, void* d_ws, size_t ws_size,
                              hipStream_t stream) {
    const float* x      = (const float*)d_in[0];
    const float* w_ih_f = (const float*)d_in[1];
    const float* w_hh_f = (const float*)d_in[2];
    const float* b_ih_f = (const float*)d_in[3];
    const float* b_hh_f = (const float*)d_in[4];
    const float* w_ih_b = (const float*)d_in[5];
    // d_in[6] = w_hh_b — provably unused (backward cell starts from zero state)
    const float* b_ih_b = (const float*)d_in[7];
    const float* b_hh_b = (const float*)d_in[8];
    const float* w_fc   = (const float*)d_in[9];
    const float* b_fc   = (const float*)d_in[10];
    float* out = (float*)d_out;

    const int B = out_size;                 // 512
    const int T = in_sizes[0] / (B * 4);    // 1000

    bilstm_kernel<<<dim3(B), dim3(64), 0, stream>>>(
        x, w_ih_f, w_hh_f, b_ih_f, b_hh_f,
        w_ih_b, b_ih_b, b_hh_b, w_fc, b_fc, out, T);
}

// Round 2
// 625.262 us; speedup vs baseline: 2.0414x; 2.0414x over previous
//
#include <hip/hip_runtime.h>

#define HDIM 64

__device__ __forceinline__ float fast_sigmoid(float v) {
    return __builtin_amdgcn_rcpf(1.0f + __builtin_amdgcn_exp2f(-1.442695041f * v));
}

__device__ __forceinline__ float fast_tanh(float v) {
    return 1.0f - 2.0f * __builtin_amdgcn_rcpf(1.0f + __builtin_amdgcn_exp2f(2.885390082f * v));
}

// 256 threads = 4 waves per batch element.
// lane l (0..63) of wave w owns gate-row r = j*64 + m, where
//   j = l>>4  (gate: 0=i,1=f,2=g,3=o),  m = w*16 + (l&15)  (output index).
// Recurrent weights for the row live in 16 float4 VGPRs.
__global__ __launch_bounds__(256, 2)
void bilstm_kernel(const float* __restrict__ x,
                   const float* __restrict__ w_ih_f,
                   const float* __restrict__ w_hh_f,
                   const float* __restrict__ b_ih_f,
                   const float* __restrict__ b_hh_f,
                   const float* __restrict__ w_ih_b,
                   const float* __restrict__ b_ih_b,
                   const float* __restrict__ b_hh_b,
                   const float* __restrict__ w_fc,
                   const float* __restrict__ b_fc,
                   float* __restrict__ out,
                   int T)
{
    const int b   = blockIdx.x;
    const int tid = threadIdx.x;
    const int w   = tid >> 6;        // wave 0..3
    const int l   = tid & 63;        // lane 0..63
    const int j   = l >> 4;          // gate id
    const int m   = (w << 4) | (l & 15);   // output index 0..63
    const int r   = (j << 6) | m;          // row in [0,256)

    __shared__ float hbuf[2][HDIM];

    // ---- per-lane weights into registers ----
    float4 wv[16];
    {
        const float* row = w_hh_f + (size_t)r * HDIM;
        #pragma unroll
        for (int q = 0; q < 16; ++q) wv[q] = *(const float4*)(row + 4 * q);
    }
    float4 wx = *(const float4*)(w_ih_f + (size_t)r * 4);
    const float bz = b_ih_f[r] + b_hh_f[r];

    // init h buffer 0
    if (tid < HDIM) hbuf[0][tid] = 0.0f;
    __syncthreads();

    const float* xb = x + (size_t)b * T * 4;
    float4 xcur = *(const float4*)(xb);   // t = 0
    float c = 0.0f, h = 0.0f;
    int rb = 0;

    for (int t = 0; t < T; ++t) {
        // prefetch next x (clamped)
        const int tn = (t + 1 < T) ? t + 1 : T - 1;
        float4 xnext = *(const float4*)(xb + 4 * tn);

        float a = bz;
        const float4* hp = (const float4*)hbuf[rb];
        #pragma unroll
        for (int q = 0; q < 16; ++q) {
            float4 hq = hp[q];               // broadcast read (same addr all lanes)
            a += wv[q].x * hq.x;
            a += wv[q].y * hq.y;
            a += wv[q].z * hq.z;
            a += wv[q].w * hq.w;
        }
        a += wx.x * xcur.x + wx.y * xcur.y + wx.z * xcur.z + wx.w * xcur.w;

        // activation: sigmoid for j=0,1,3 ; tanh for j=2  (one exp + one rcp)
        const float s = (j == 2) ? 2.885390082f : -1.442695041f;
        const float e = __builtin_amdgcn_exp2f(s * a);
        const float rr = __builtin_amdgcn_rcpf(1.0f + e);
        const float gv = (j == 2) ? 1.0f - 2.0f * rr : rr;

        // gather the 4 gate values of output m (lanes l, l^16, l^32, l^48)
        const float v1 = __shfl_xor(gv, 16);
        const float pe = ((j & 1) == 0) ? gv : v1;   // i (j<2) or g (j>=2)
        const float po = ((j & 1) == 0) ? v1 : gv;   // f (j<2) or o (j>=2)
        const float qe = __shfl_xor(pe, 32);
        const float qo = __shfl_xor(po, 32);
        const float gi = (j < 2) ? pe : qe;
        const float gf = (j < 2) ? po : qo;
        const float gg = (j < 2) ? qe : pe;
        const float go = (j < 2) ? qo : po;

        // cell update (redundant across the 4 gate-groups; identical inputs)
        c = gf * c + gi * gg;
        h = go * fast_tanh(c);

        if (l < 16) hbuf[rb ^ 1][(w << 4) | l] = h;   // j==0 lanes write h[m]
        __syncthreads();
        rb ^= 1;
        xcur = xnext;
    }

    // ---- epilogue: wave 0 handles backward cell + fc + sigmoid ----
    if (w == 0) {
        // backward-direction single cell from zero state at x[:, T-1]
        // (w_hh_b never multiplies nonzero state). xcur == x[:, T-1].
        float gb[4];
        #pragma unroll
        for (int jj = 0; jj < 4; ++jj) {
            const int rr2 = (jj << 6) | l;
            float4 wb = *(const float4*)(w_ih_b + (size_t)rr2 * 4);
            gb[jj] = b_ih_b[rr2] + b_hh_b[rr2]
                   + wb.x * xcur.x + wb.y * xcur.y + wb.z * xcur.z + wb.w * xcur.w;
        }
        const float ib  = fast_sigmoid(gb[0]);
        const float ggb = fast_tanh(gb[2]);
        const float ob  = fast_sigmoid(gb[3]);
        const float cb  = ib * ggb;
        const float hb  = ob * fast_tanh(cb);

        const float hf = hbuf[rb][l];     // final forward h (rb points at last-written buf)
        float p = w_fc[l] * hf + w_fc[HDIM + l] * hb;
        #pragma unroll
        for (int off = 32; off; off >>= 1) p += __shfl_xor(p, off);

        if (l == 0) out[b] = fast_sigmoid(p + b_fc[0]);
    }
}

extern "C" void kernel_launch(void* const* d_in, const int* in_sizes, int n_in,
                              void* d_out, int out_size, void* d_ws, size_t ws_size,
                              hipStream_t stream) {
    const float* x      = (const float*)d_in[0];
    const float* w_ih_f = (const float*)d_in[1];
    const float* w_hh_f = (const float*)d_in[2];
    const float* b_ih_f = (const float*)d_in[3];
    const float* b_hh_f = (const float*)d_in[4];
    const float* w_ih_b = (const float*)d_in[5];
    // d_in[6] = w_hh_b — unused (backward cell starts from zero state)
    const float* b_ih_b = (const float*)d_in[7];
    const float* b_hh_b = (const float*)d_in[8];
    const float* w_fc   = (const float*)d_in[9];
    const float* b_fc   = (const float*)d_in[10];
    float* out = (float*)d_out;

    const int B = out_size;                 // 512
    const int T = in_sizes[0] / (B * 4);    // 1000

    bilstm_kernel<<<dim3(B), dim3(256), 0, stream>>>(
        x, w_ih_f, w_hh_f, b_ih_f, b_hh_f,
        w_ih_b, b_ih_b, b_hh_b, w_fc, b_fc, out, T);
}